// Round 1
// 599.642 us; speedup vs baseline: 1.1420x; 1.1420x over previous
//
#include <hip/hip_runtime.h>
#include <cstdint>
#include <cstddef>

typedef __attribute__((ext_vector_type(8))) short bf16x8;   // 8 bf16 = 4 VGPRs
typedef __attribute__((ext_vector_type(4))) float floatx4;  // MFMA C/D frag

#define NBATCH 16
#define CIN    512
#define COUT   512
#define HH     64
#define WW     64
#define HP     66                 // padded H/W (+1 halo each side)

// LDS geometry (ushort units). Linear layouts (required by global_load_lds),
// bank conflicts handled by XOR chunk swizzle baked into the GLOBAL source
// address (m173 pattern): LDS[slot][ch] holds global chunk ch^(slot&7).
#define XCOLS  72                  // 66 live cols padded to 72 -> uniform 9 loads/thread
#define XUS    (4 * XCOLS * 64)    // 18432 ushorts = 36864 B  (4 rows x 72 cols x 64 c)
#define AUS    (128 * 64)          // 8192 ushorts = 16384 B   (128 o x 64 c), x2 buffers

static __device__ __forceinline__ unsigned short f2bf(float f) {
  union { float f; unsigned u; } cv; cv.f = f;
  unsigned u = cv.u;
  return (unsigned short)((u + 0x7FFFu + ((u >> 16) & 1u)) >> 16);  // RNE
}

// async 16B global -> LDS DMA. LDS dest is wave-uniform base + lane*16 (m104);
// global source is per-lane (m173).
static __device__ __forceinline__ void async16(const unsigned short* g, unsigned short* l) {
  __builtin_amdgcn_global_load_lds(
      (const __attribute__((address_space(1))) void*)g,
      (__attribute__((address_space(3))) void*)l, 16, 0, 0);
}

// K0: zero only the halo border of xmp (replaces 71MB memset with 4.3MB of stores)
__global__ void k_zero(unsigned short* __restrict__ xmp) {
  int slot = blockIdx.x;           // 0..259 border slots per image
  int n    = blockIdx.y;
  int h, w;
  if (slot < 66)       { h = 0;              w = slot;       }
  else if (slot < 132) { h = 65;             w = slot - 66;  }
  else if (slot < 196) { h = slot - 132 + 1; w = 0;          }
  else                 { h = slot - 196 + 1; w = 65;         }
  unsigned* p = (unsigned*)(xmp + (((size_t)n * HP + h) * HP + w) * CIN);
  p[threadIdx.x] = 0u;             // 256 thr x 4B = 1KB = full 512-ch slot
}

// K1: w2t[c][o] = sum_r w[o][c][r]^2 ; wr[r][o][c] = bf16(w[o][c][r])
__global__ void k_wprep(const float* __restrict__ w, unsigned short* __restrict__ wr,
                        float* __restrict__ w2t) {
  int o = blockIdx.x;
  int c = blockIdx.y * 256 + threadIdx.x;
  const float* wp = w + ((size_t)o * CIN + c) * 9;
  float v[9]; float sum = 0.f;
#pragma unroll
  for (int r = 0; r < 9; ++r) { v[r] = wp[r]; sum += v[r] * v[r]; }
  w2t[(size_t)c * COUT + o] = sum;
#pragma unroll
  for (int r = 0; r < 9; ++r)
    wr[((size_t)r * COUT + o) * CIN + c] = f2bf(v[r]);
}

// K2: d[n][o] = rsqrt(sum_c s[n][c]^2 * w2t[c][o] + 1e-8)
__global__ void k_dcoef(const float* __restrict__ s, const float* __restrict__ w2t,
                        float* __restrict__ d) {
  __shared__ float s2[CIN];
  int n = blockIdx.y;
  int o = blockIdx.x * 256 + threadIdx.x;
  for (int c = threadIdx.x; c < CIN; c += 256) {
    float sv = s[n * CIN + c]; s2[c] = sv * sv;
  }
  __syncthreads();
  float sum = 0.f;
  for (int c = 0; c < CIN; ++c) sum += s2[c] * w2t[(size_t)c * COUT + o];
  d[n * COUT + o] = rsqrtf(sum + 1e-8f);
}

// K3: xmp[n][h+1][w+1][c] = bf16(x[n][c][h][w] * s[n][c]); NHWC padded
__global__ void k_xmod(const float* __restrict__ x, const float* __restrict__ s,
                       unsigned short* __restrict__ xmp) {
  __shared__ __align__(16) unsigned short tile[WW * 520];
  int tid  = threadIdx.x;
  int n    = blockIdx.x >> 6;
  int h    = blockIdx.x & 63;
  int wcol = tid & 63;
  int grp  = tid >> 6;
#pragma unroll
  for (int i = 0; i < 16; ++i) {
    int c0 = (i * 4 + grp) * 8;
    bf16x8 pk;
#pragma unroll
    for (int j = 0; j < 8; ++j) {
      int c = c0 + j;
      float v = x[(((size_t)n * CIN + c) * HH + h) * WW + wcol] * s[n * CIN + c];
      pk[j] = (short)f2bf(v);
    }
    *(bf16x8*)(tile + wcol * 520 + c0) = pk;
  }
  __syncthreads();
#pragma unroll
  for (int i = 0; i < 16; ++i) {
    int wv = i * 4 + grp;
    bf16x8 v = *(const bf16x8*)(tile + wv * 520 + wcol * 8);
    *(bf16x8*)(xmp + (((size_t)n * HP + (h + 1)) * HP + (wv + 1)) * CIN + wcol * 8) = v;
  }
}

// Main: shift-GEMM modulated conv, pipelined schedule.
//  - All LDS staging via global_load_lds dwordx4 (no ds_write at all).
//  - W tiles double-buffered; raw s_barrier + counted vmcnt(4): prefetch stays
//    in flight across barriers (T3+T4), never drains to 0 except at r==8.
//  - XOR chunk swizzle (chunk ^= slot&7) applied on the global source address
//    and on the ds_read offset -> conflict-free b128 reads on a linear layout.
__global__ __launch_bounds__(256, 2)
void k_conv(const unsigned short* __restrict__ xmp, const unsigned short* __restrict__ wr,
            const float* __restrict__ d, const float* __restrict__ bias,
            const float* __restrict__ noise, float* __restrict__ out) {
  __shared__ __align__(16) unsigned short smem[XUS + 2 * AUS];   // 69632 B -> 2 blocks/CU
  unsigned short* Xs  = smem;
  unsigned short* As0 = smem + XUS;
  unsigned short* As1 = smem + XUS + AUS;

  const int tid  = threadIdx.x;
  const int lane = tid & 63;
  const int l15  = lane & 15;
  const int quad = lane >> 4;
  const int wv   = tid >> 6;
  const int wrow = wv & 1;     // which of the 2 pixel rows this wave owns
  const int woc  = wv >> 1;    // which 64-wide Cout half

  const int bx  = blockIdx.x;
  const int n   = bx >> 5;
  const int h0  = (bx & 31) * 2;        // padded patch rows h0..h0+3
  const int ocb = blockIdx.y * 128;

  floatx4 acc[4][4];
#pragma unroll
  for (int a = 0; a < 4; ++a)
#pragma unroll
    for (int b = 0; b < 4; ++b)
#pragma unroll
      for (int q = 0; q < 4; ++q) acc[a][b][q] = 0.f;

  // X stage: wave wv owns padded row h0+wv; 9 uniform DMA loads per thread.
  // LDS chunk index = wv*576 + t*64 + lane; cols 66..71 clamped (slots never read).
  auto stageX = [&](int cb) {
    const int c0 = cb * 64;
    const size_t grow = ((size_t)n * HP + (h0 + wv)) * HP;
#pragma unroll
    for (int t = 0; t < 9; ++t) {
      int ci   = t * 64 + lane;          // chunk-in-row 0..575
      int col  = ci >> 3;
      int ch   = ci & 7;
      int colc = (col < 66) ? col : 65;  // clamp: uniform count, in-bounds
      const unsigned short* g = xmp + (grow + colc) * CIN + c0 + ((ch ^ (col & 7)) << 3);
      unsigned short* l = Xs + ((wv * 576 + t * 64) << 3);   // wave-uniform base
      async16(g, l);
    }
  };
  // W stage: 1024 chunks, 4 uniform DMA loads per thread.
  auto stageW = [&](int r, int cb, unsigned short* buf) {
    const int c0 = cb * 64;
#pragma unroll
    for (int t = 0; t < 4; ++t) {
      int ci = wv * 256 + t * 64 + lane;
      int ol = ci >> 3;
      int ch = ci & 7;
      const unsigned short* g =
          wr + ((size_t)(r * COUT) + ocb + ol) * CIN + c0 + ((ch ^ (ol & 7)) << 3);
      unsigned short* l = buf + ((wv * 256 + t * 64) << 3);  // wave-uniform base
      async16(g, l);
    }
  };

  unsigned short* Asel[2] = {As0, As1};

  stageX(0);
  stageW(0, 0, As0);           // 13 loads in flight

  for (int cb = 0; cb < 8; ++cb) {
#pragma unroll
    for (int r = 0; r < 9; ++r) {
      if (r < 8) stageW(r + 1, cb, Asel[(r + 1) & 1]);   // 4 more in flight
      // Wait for everything except the 4 just-issued prefetch loads.
      if (r < 8) asm volatile("s_waitcnt vmcnt(4)" ::: "memory");
      else       asm volatile("s_waitcnt vmcnt(0)" ::: "memory");
      __builtin_amdgcn_s_barrier();
      asm volatile("" ::: "memory");    // no LDS reads hoisted above the barrier

      const unsigned short* Ab = Asel[r & 1];
      const int kh = r / 3, kw = r - (r / 3) * 3;
      const int xb = (wrow + kh) * XCOLS;
      __builtin_amdgcn_s_setprio(1);
#pragma unroll
      for (int ks = 0; ks < 2; ++ks) {
        bf16x8 af[4], bv[4];
#pragma unroll
        for (int mf = 0; mf < 4; ++mf) {
          int cpos = ((ks << 2) | quad) ^ (l15 & 7);           // o_l&7 == l15&7
          af[mf] = *(const bf16x8*)(Ab + ((woc * 64 + mf * 16 + l15) << 6) + (cpos << 3));
        }
#pragma unroll
        for (int nf = 0; nf < 4; ++nf) {
          int slot = xb + nf * 16 + l15 + kw;
          int cpos = ((ks << 2) | quad) ^ ((l15 + kw) & 7);    // slot&7 == (l15+kw)&7
          bv[nf] = *(const bf16x8*)(Xs + (slot << 6) + (cpos << 3));
        }
#pragma unroll
        for (int mf = 0; mf < 4; ++mf)
#pragma unroll
          for (int nf = 0; nf < 4; ++nf)
            acc[mf][nf] = __builtin_amdgcn_mfma_f32_16x16x32_bf16(af[mf], bv[nf], acc[mf][nf], 0, 0, 0);
      }
      __builtin_amdgcn_s_setprio(0);
      asm volatile("" ::: "memory");    // reads can't sink below the barrier
      __builtin_amdgcn_s_barrier();     // frees As[(r+1)&1] / (at r==8) Xs
    }
    if (cb < 7) {                       // next c-block: X + W(0) DMA, waited next phase
      stageX(cb + 1);
      stageW(0, cb + 1, As0);
    }
  }

  // ---- fused epilogue: out = leakyrelu(acc * d[n,o] + b[o] + noise)
  int h = h0 + wrow;
#pragma unroll
  for (int mf = 0; mf < 4; ++mf) {
#pragma unroll
    for (int i = 0; i < 4; ++i) {
      int o = ocb + woc * 64 + mf * 16 + quad * 4 + i;
      float dd = d[n * COUT + o];
      float bb = bias[o];
      size_t base = (((size_t)n * COUT + o) * HH + h) * WW;
#pragma unroll
      for (int nf = 0; nf < 4; ++nf) {
        int wc = nf * 16 + l15;
        float v = acc[mf][nf][i] * dd + bb + noise[base + wc];
        out[base + wc] = (v >= 0.f) ? v : 0.2f * v;
      }
    }
  }
}

extern "C" void kernel_launch(void* const* d_in, const int* in_sizes, int n_in,
                              void* d_out, int out_size, void* d_ws, size_t ws_size,
                              hipStream_t stream) {
  (void)in_sizes; (void)n_in; (void)out_size; (void)ws_size;
  const float* x     = (const float*)d_in[0];
  const float* s     = (const float*)d_in[1];
  const float* noise = (const float*)d_in[2];
  const float* w     = (const float*)d_in[3];
  const float* bias  = (const float*)d_in[4];
  float* out = (float*)d_out;

  char* ws = (char*)d_ws;
  const size_t XMP_BYTES = (size_t)NBATCH * HP * HP * CIN * 2;  // 71,368,704
  const size_t WR_BYTES  = (size_t)9 * COUT * CIN * 2;          //  4,718,592
  const size_t W2_BYTES  = (size_t)CIN * COUT * 4;              //  1,048,576
  unsigned short* xmp = (unsigned short*)ws;
  unsigned short* wrr = (unsigned short*)(ws + XMP_BYTES);
  float* w2t          = (float*)(ws + XMP_BYTES + WR_BYTES);
  float* dcoef        = (float*)(ws + XMP_BYTES + WR_BYTES + W2_BYTES);

  k_zero <<<dim3(260, NBATCH), 256, 0, stream>>>(xmp);          // border halo only
  k_wprep<<<dim3(COUT, 2),  256, 0, stream>>>(w, wrr, w2t);
  k_dcoef<<<dim3(2, NBATCH), 256, 0, stream>>>(s, w2t, dcoef);
  k_xmod <<<dim3(NBATCH * HH), 256, 0, stream>>>(x, s, xmp);
  k_conv <<<dim3(NBATCH * HH / 2, COUT / 128), 256, 0, stream>>>(xmp, wrr, dcoef, bias, noise, out);
}

// Round 4
// 564.994 us; speedup vs baseline: 1.2120x; 1.0613x over previous
//
#include <hip/hip_runtime.h>
#include <cstdint>
#include <cstddef>

typedef __attribute__((ext_vector_type(8))) short bf16x8;   // 8 bf16 = 4 VGPRs
typedef __attribute__((ext_vector_type(4))) float floatx4;  // MFMA C/D frag

#define NBATCH 16
#define CIN    512
#define COUT   512
#define HH     64
#define WW     64
#define HP     66                 // padded H/W (+1 halo each side)

// X LDS: linear (required by global_load_lds), XOR chunk swizzle baked into the
// GLOBAL source address (m173 pattern): LDS[row][col][ch] holds global chunk ch^(col&7).
#define XCOLS  72                  // 66 live cols padded to 72 -> uniform 9 loads/thread
#define XUS    (4 * XCOLS * 64)    // 18432 ushorts = 36864 B per buffer (x2 buffers)

static __device__ __forceinline__ unsigned short f2bf(float f) {
  union { float f; unsigned u; } cv; cv.f = f;
  unsigned u = cv.u;
  return (unsigned short)((u + 0x7FFFu + ((u >> 16) & 1u)) >> 16);  // RNE
}

static __device__ __forceinline__ void async16(const unsigned short* g, unsigned short* l) {
  __builtin_amdgcn_global_load_lds(
      (const __attribute__((address_space(1))) void*)g,
      (__attribute__((address_space(3))) void*)l, 16, 0, 0);
}

// K0: zero the halo border of xmp (260 slots x 16 images, 1KB per slot)
__global__ void k_zero(unsigned short* __restrict__ xmp) {
  int slot = blockIdx.x;           // 0..259 border slots
  int h, w;
  if (slot < 66)       { h = 0;              w = slot;       }
  else if (slot < 132) { h = 65;             w = slot - 66;  }
  else if (slot < 196) { h = slot - 132 + 1; w = 0;          }
  else                 { h = slot - 196 + 1; w = 65;         }
  for (int n = 0; n < NBATCH; ++n) {
    unsigned* p = (unsigned*)(xmp + (((size_t)n * HP + h) * HP + w) * CIN);
    p[threadIdx.x] = 0u;
  }
}

// K1: w2t[c][o] = sum_r w[o][c][r]^2 ;
//     wfrag fragment-linear: [r][cb][ob][ks][lane][j] so a wave's A-fragment
//     load in k_conv is one coalesced 1KB global_load_dwordx4 per (r,cb,ob,ks).
//     o = ob*16 + l15 (lane = quad*16+l15), c = cb*64 + ks*32 + quad*8 + j.
__global__ void k_wprep(const float* __restrict__ w, unsigned short* __restrict__ wfrag,
                        float* __restrict__ w2t) {
  int o = blockIdx.x;
  int c = blockIdx.y * 256 + threadIdx.x;
  const float* wp = w + ((size_t)o * CIN + c) * 9;
  float v[9]; float sum = 0.f;
#pragma unroll
  for (int r = 0; r < 9; ++r) { v[r] = wp[r]; sum += v[r] * v[r]; }
  w2t[(size_t)c * COUT + o] = sum;
  int ob = o >> 4, l15 = o & 15;
  int cb = c >> 6, ks = (c >> 5) & 1, quad = (c >> 3) & 3, j = c & 7;
#pragma unroll
  for (int r = 0; r < 9; ++r)
    wfrag[((((size_t)r * 8 + cb) * 32 + ob) * 2 + ks) * 512 + (quad * 16 + l15) * 8 + j] = f2bf(v[r]);
}

// K2: d[n][o] = rsqrt(sum_c s[n][c]^2 * w2t[c][o] + 1e-8)
__global__ void k_dcoef(const float* __restrict__ s, const float* __restrict__ w2t,
                        float* __restrict__ d) {
  __shared__ float s2[CIN];
  int n = blockIdx.y;
  int o = blockIdx.x * 256 + threadIdx.x;
  for (int c = threadIdx.x; c < CIN; c += 256) {
    float sv = s[n * CIN + c]; s2[c] = sv * sv;
  }
  __syncthreads();
  float sum = 0.f;
  for (int c = 0; c < CIN; ++c) sum += s2[c] * w2t[(size_t)c * COUT + o];
  d[n * COUT + o] = rsqrtf(sum + 1e-8f);
}

// K3: xmp[n][h+1][w+1][c] = bf16(x[n][c][h][w] * s[n][c]); NHWC padded
__global__ void k_xmod(const float* __restrict__ x, const float* __restrict__ s,
                       unsigned short* __restrict__ xmp) {
  __shared__ __align__(16) unsigned short tile[WW * 520];
  int tid  = threadIdx.x;
  int n    = blockIdx.x >> 6;
  int h    = blockIdx.x & 63;
  int wcol = tid & 63;
  int grp  = tid >> 6;
#pragma unroll
  for (int i = 0; i < 16; ++i) {
    int c0 = (i * 4 + grp) * 8;
    bf16x8 pk;
#pragma unroll
    for (int j = 0; j < 8; ++j) {
      int c = c0 + j;
      float v = x[(((size_t)n * CIN + c) * HH + h) * WW + wcol] * s[n * CIN + c];
      pk[j] = (short)f2bf(v);
    }
    *(bf16x8*)(tile + wcol * 520 + c0) = pk;
  }
  __syncthreads();
#pragma unroll
  for (int i = 0; i < 16; ++i) {
    int wv = i * 4 + grp;
    bf16x8 v = *(const bf16x8*)(tile + wv * 520 + wcol * 8);
    *(bf16x8*)(xmp + (((size_t)n * HP + (h + 1)) * HP + (wv + 1)) * CIN + wcol * 8) = v;
  }
}

// Main: shift-GEMM modulated conv.
//  - W fragments load global->VGPR directly (fragment-linear wfrag, L2-resident):
//    no W LDS staging, no in-loop barriers at all.
//  - X double-buffered in LDS via global_load_lds; ONE vmcnt(0)+barrier per c-block.
//  - W register ping-pong with compile-time parity only (rule #20).
__global__ __launch_bounds__(256, 2)
void k_conv(const unsigned short* __restrict__ xmp, const unsigned short* __restrict__ wfrag,
            const float* __restrict__ d, const float* __restrict__ bias,
            const float* __restrict__ noise, float* __restrict__ out) {
  __shared__ __align__(16) unsigned short smem[2 * XUS];   // 73728 B -> 2 blocks/CU

  const int tid  = threadIdx.x;
  const int lane = tid & 63;
  const int l15  = lane & 15;
  const int quad = lane >> 4;
  const int wv   = tid >> 6;
  const int wrow = wv & 1;     // which of the 2 pixel rows this wave owns
  const int woc  = wv >> 1;    // which 64-wide Cout half

  // XCD-aware decode (bijective over 0..2047): xcd = i&7 pairs own one 128-Cout
  // slice -> that slice's wfrag (1.18 MB) stays resident in the XCD's L2.
  const int i    = blockIdx.x;          // 0..2047
  const int ybl  = (i & 7) >> 1;        // Cout block 0..3
  const int lin  = ((i & 1) << 8) | (i >> 3);   // 0..511, bijective with ybl fixed
  const int n    = lin >> 5;
  const int h0   = (lin & 31) * 2;      // padded patch rows h0..h0+3
  const int ob0  = ybl * 8 + woc * 4;   // A-fragment ob base (o = ob*16+l15)

  floatx4 acc[4][4];
#pragma unroll
  for (int a = 0; a < 4; ++a)
#pragma unroll
    for (int b = 0; b < 4; ++b)
#pragma unroll
      for (int q = 0; q < 4; ++q) acc[a][b][q] = 0.f;

  // X stage: wave wv owns padded row h0+wv; 9 uniform DMA loads per thread.
  auto stageX = [&](int cb, unsigned short* Xdst) {
    const int c0 = cb * 64;
    const size_t grow = ((size_t)n * HP + (h0 + wv)) * HP;
#pragma unroll
    for (int t = 0; t < 9; ++t) {
      int ci   = t * 64 + lane;          // chunk-in-row 0..575
      int col  = ci >> 3;
      int ch   = ci & 7;
      int colc = (col < 66) ? col : 65;  // clamp: uniform count, in-bounds
      const unsigned short* g = xmp + (grow + colc) * CIN + c0 + ((ch ^ (col & 7)) << 3);
      async16(g, Xdst + ((wv * 576 + t * 64) << 3));
    }
  };

  // A-fragment register load: 8 x coalesced 1KB wave-loads from L2-resident wfrag.
  auto loadW = [&](int r, int cb, bf16x8* dst) {
#pragma unroll
    for (int ks = 0; ks < 2; ++ks)
#pragma unroll
      for (int mf = 0; mf < 4; ++mf)
        dst[ks * 4 + mf] = *(const bf16x8*)(
            wfrag + ((((size_t)r * 8 + cb) * 32 + (ob0 + mf)) * 2 + ks) * 512 + lane * 8);
  };

  bf16x8 afA[8], afB[8];

  // One c-block: 9 barrier-free phases of {W-prefetch, 8 ds_read, 32 MFMA}.
  // f0 holds W(r=0) on entry; compile-time parity ping-pong.
  auto convCB = [&](int cb, bf16x8* f0, bf16x8* f1) {
    unsigned short* Xs = smem + (cb & 1) * XUS;
    if (cb < 7) stageX(cb + 1, smem + ((cb + 1) & 1) * XUS);
#pragma unroll
    for (int r = 0; r < 9; ++r) {
      bf16x8* cur = (r & 1) ? f1 : f0;
      bf16x8* nxt = (r & 1) ? f0 : f1;
      if (r < 8)      loadW(r + 1, cb, nxt);
      else if (cb < 7) loadW(0, cb + 1, nxt);
      const int kh = r / 3, kw = r - (r / 3) * 3;
      const int xb = (wrow + kh) * XCOLS;
      __builtin_amdgcn_s_setprio(1);
#pragma unroll
      for (int ks = 0; ks < 2; ++ks) {
        bf16x8 bv[4];
#pragma unroll
        for (int nf = 0; nf < 4; ++nf) {
          int slot = xb + nf * 16 + l15 + kw;
          int cpos = ((ks << 2) | quad) ^ ((l15 + kw) & 7);    // slot&7 == (l15+kw)&7
          bv[nf] = *(const bf16x8*)(Xs + (slot << 6) + (cpos << 3));
        }
#pragma unroll
        for (int mf = 0; mf < 4; ++mf)
#pragma unroll
          for (int nf = 0; nf < 4; ++nf)
            acc[mf][nf] = __builtin_amdgcn_mfma_f32_16x16x32_bf16(cur[ks * 4 + mf], bv[nf], acc[mf][nf], 0, 0, 0);
      }
      __builtin_amdgcn_s_setprio(0);
    }
    // X(cb+1) ready for everyone before next c-block reads it.
    asm volatile("s_waitcnt vmcnt(0)" ::: "memory");
    __builtin_amdgcn_s_barrier();
    asm volatile("" ::: "memory");
  };

  // prologue
  stageX(0, smem);
  loadW(0, 0, afA);
  asm volatile("s_waitcnt vmcnt(0)" ::: "memory");
  __builtin_amdgcn_s_barrier();
  asm volatile("" ::: "memory");

#pragma unroll 1
  for (int c2 = 0; c2 < 4; ++c2) {     // 9 phases (odd) flips parity each cb
    convCB(2 * c2,     afA, afB);
    convCB(2 * c2 + 1, afB, afA);
  }

  // ---- fused epilogue: out = leakyrelu(acc * d[n,o] + b[o] + noise)
  int h = h0 + wrow;
  int ocb = ybl * 128;
#pragma unroll
  for (int mf = 0; mf < 4; ++mf) {
#pragma unroll
    for (int ii = 0; ii < 4; ++ii) {
      int o = ocb + woc * 64 + mf * 16 + quad * 4 + ii;
      float dd = d[n * COUT + o];
      float bb = bias[o];
      size_t base = (((size_t)n * COUT + o) * HH + h) * WW;
#pragma unroll
      for (int nf = 0; nf < 4; ++nf) {
        int wc = nf * 16 + l15;        // lanes contiguous along w -> coalesced
        float v = acc[mf][nf][ii] * dd + bb + noise[base + wc];
        out[base + wc] = (v >= 0.f) ? v : 0.2f * v;
      }
    }
  }
}

extern "C" void kernel_launch(void* const* d_in, const int* in_sizes, int n_in,
                              void* d_out, int out_size, void* d_ws, size_t ws_size,
                              hipStream_t stream) {
  (void)in_sizes; (void)n_in; (void)out_size; (void)ws_size;
  const float* x     = (const float*)d_in[0];
  const float* s     = (const float*)d_in[1];
  const float* noise = (const float*)d_in[2];
  const float* w     = (const float*)d_in[3];
  const float* bias  = (const float*)d_in[4];
  float* out = (float*)d_out;

  char* ws = (char*)d_ws;
  const size_t XMP_BYTES = (size_t)NBATCH * HP * HP * CIN * 2;  // 71,368,704
  const size_t WF_BYTES  = (size_t)9 * COUT * CIN * 2;          //  4,718,592
  const size_t W2_BYTES  = (size_t)CIN * COUT * 4;              //  1,048,576
  unsigned short* xmp   = (unsigned short*)ws;
  unsigned short* wfrag = (unsigned short*)(ws + XMP_BYTES);
  float* w2t            = (float*)(ws + XMP_BYTES + WF_BYTES);
  float* dcoef          = (float*)(ws + XMP_BYTES + WF_BYTES + W2_BYTES);

  k_zero <<<dim3(260),       256, 0, stream>>>(xmp);
  k_wprep<<<dim3(COUT, 2),   256, 0, stream>>>(w, wfrag, w2t);
  k_dcoef<<<dim3(2, NBATCH), 256, 0, stream>>>(s, w2t, dcoef);
  k_xmod <<<dim3(NBATCH * HH), 256, 0, stream>>>(x, s, xmp);
  // 2048 blocks: full (ybl, n, h0) space — R2 bug was launching only 512 here.
  k_conv <<<dim3(NBATCH * HH / 2 * (COUT / 128)), 256, 0, stream>>>(xmp, wfrag, dcoef, bias, noise, out);
}